// Round 10
// baseline (326.904 us; speedup 1.0000x reference)
//
#include <hip/hip_runtime.h>
#include <hip/hip_cooperative_groups.h>
#include <math.h>

namespace cg = cooperative_groups;

#define NN 4096
#define RCAP 256          // per-row bucket capacity (mean 80, max ~130)
#define CPAD 16           // counter stride in ints: one counter per 64B line
#define GB 512            // grid blocks (4/CU x 256 CU = 1024 capacity)
#define BT 256
#define HS2 1024          // per-quad LDS hash slots
#define NBC 128           // colsum partial sets

// mysign(|v|) - 0.5 with reference-faithful overflow: e=inf -> NaN
__device__ __forceinline__ float smh(float v) {
    float e = expf(6.0f * fabsf(v));
    return 0.5f * (e - 1.0f) / (e + 1.0f);
}

__global__ __launch_bounds__(BT, 4) void fused_k(
    const int2* __restrict__ edges, const float* __restrict__ weights,
    const float* __restrict__ stat, const int2* __restrict__ edges_c,
    const float* __restrict__ grdt, const int* __restrict__ targets,
    int E, int EC, int T,
    int* __restrict__ row_cnt, float4* __restrict__ rowbuf,
    int2* __restrict__ out_rc, int* __restrict__ cnt2,
    float* __restrict__ nout, float* __restrict__ part,
    float* __restrict__ good_buf, float* __restrict__ out) {

    cg::grid_group grid = cg::this_grid();
    __shared__ union {
        struct { int key[HS2]; float A[HS2], W[HS2], B[HS2]; } h;   // 16KB
        struct { float g[NN], n[NN]; } c;                            // 32KB
    } S;
    __shared__ int s_n[4];
    __shared__ float s_acc[4];

    const int b = blockIdx.x, t = threadIdx.x;
    const int wv = t >> 6, lane = t & 63;
    const int gtid = b * BT + t;
    const int total = E + EC;

    // ---- P0: zero row counters (NN*CPAD ints = 16384 int4) ----
    if (gtid < NN * CPAD / 4)
        ((int4*)row_cnt)[gtid] = make_int4(0, 0, 0, 0);
    grid.sync();

    // ---- P1: bucket records by row (padded atomic counter + plain store) --
    for (int i = gtid; i < total; i += GB * BT) {
        int2 rc; float f0, f1 = 0.f; int isC;
        if (i < E) { rc = edges[i]; f0 = stat[i]; f1 = weights[i]; isC = 0; }
        else { int j = i - E; rc = edges_c[j]; f0 = grdt[j]; isC = 1; }
        int pos = atomicAdd(&row_cnt[rc.x * CPAD], 1);
        if (pos < RCAP) {
            float4 rec;
            rec.x = __int_as_float((rc.y << 1) | isC);
            rec.y = f0;      // stat (A) or grdt (B)
            rec.z = f1;      // weight (W) or unused
            rec.w = 0.f;
            rowbuf[rc.x * RCAP + pos] = rec;
        }
    }
    grid.sync();

    // ---- P2: coalesce duplicates (scatter-add semantics), 8 rows/block ----
    for (int rq = 0; rq < 2; ++rq) {
        for (int i = t; i < HS2; i += BT) {
            S.h.key[i] = -1; S.h.A[i] = 0.f; S.h.W[i] = 0.f; S.h.B[i] = 0.f;
        }
        if (t < 4) { s_n[t] = 0; s_acc[t] = 0.f; }
        __syncthreads();
        {   // wave wv owns row r
            int r = b * 8 + rq * 4 + wv;
            int cnt = row_cnt[r * CPAD]; if (cnt > RCAP) cnt = RCAP;
            for (int i = lane; i < cnt; i += 64) {
                float4 rec = rowbuf[r * RCAP + i];
                int ct = __float_as_int(rec.x);
                int key = (wv << 12) | (ct >> 1);
                int slot = (int)(((unsigned)key * 2654435761u) >> 18) & (HS2 - 1);
                while (true) {
                    int prev = atomicCAS(&S.h.key[slot], -1, key);
                    if (prev == -1 || prev == key) break;
                    slot = (slot + 1) & (HS2 - 1);
                }
                if (ct & 1) {
                    atomicAdd(&S.h.B[slot], rec.y);
                } else {
                    atomicAdd(&S.h.A[slot], rec.y);
                    atomicAdd(&S.h.W[slot], rec.z);
                }
            }
        }
        __syncthreads();
#pragma unroll
        for (int k = 0; k < HS2 / BT; ++k) {   // sweep: v = B*(A-1)+A*W
            int s = k * BT + t;
            int key = S.h.key[s];
            if (key != -1) {
                float a = S.h.A[s], w = S.h.W[s], bb = S.h.B[s];
                float v = bb * (a - 1.0f) + a * w;
                if (v != 0.0f) {               // zero cells: 0 to all sums
                    int lr = key >> 12;
                    atomicAdd(&s_acc[lr], smh(v));   // NaN propagates
                    int pos = atomicAdd(&s_n[lr], 1);
                    out_rc[(b * 8 + rq * 4 + lr) * RCAP + pos] =
                        make_int2(key & 4095, __float_as_int(v));
                }
            }
        }
        __syncthreads();
        if (t < 4) {
            nout[b * 8 + rq * 4 + t] = s_acc[t];
            cnt2[b * 8 + rq * 4 + t] = s_n[t];
        }
        __syncthreads();
    }
    grid.sync();

    // ---- P3: column partial sums (blocks 0..NBC-1, 32 rows each) ----
    if (b < NBC) {
        for (int i = t; i < NN; i += BT) { S.c.g[i] = 0.f; S.c.n[i] = 0.f; }
        __syncthreads();
#pragma unroll
        for (int j = 0; j < 8; ++j) {          // 8 rows per wave
            int r = b * 32 + wv * 8 + j;
            int cnt = cnt2[r];
            for (int i = lane; i < cnt; i += 64) {
                int2 rec = out_rc[r * RCAP + i];
                float v = __int_as_float(rec.y);
                atomicAdd(&S.c.g[rec.x], v);
                atomicAdd(&S.c.n[rec.x], smh(v));
            }
        }
        __syncthreads();
        float* myp = part + (size_t)b * (2 * NN);
        for (int i = t; i < NN; i += BT) {
            myp[i] = S.c.g[i];
            myp[NN + i] = S.c.n[i];
        }
    }
    grid.sync();

    // ---- P4: good (first 16 blocks = 4096 threads, coalesced fold) ----
    if (gtid < NN) {
        float g = 0.f, nin = 0.f;
        for (int p = 0; p < NBC; ++p) {
            g += part[(size_t)p * 2 * NN + gtid];
            nin += part[(size_t)p * 2 * NN + NN + gtid];
        }
        float Nin = 2048.0f + nin;   // 0.5 per zero cell (mysign(0)=0.5)
        float gd = 1.0f;
        if (Nin != 0.0f) {
            float x = g / Nin;
            gd = x < -1.0f ? -1.0f : (x > 1.0f ? 1.0f : x);  // NaN stays NaN
        }
        good_buf[gtid] = gd;
        out[1 + NN + gtid] = gd;
    }
    grid.sync();

    // ---- P5: fair (8 rows/block, wave per row) + gsum (last block) ----
    for (int rq = 0; rq < 2; ++rq) {
        int r = b * 8 + rq * 4 + wv;
        int cnt = cnt2[r];
        float f = 0.f;
        for (int i = lane; i < cnt; i += 64) {
            int2 rec = out_rc[r * RCAP + i];
            float v = __int_as_float(rec.y);
            f += 1.0f - 0.5f * fabsf(v - good_buf[rec.x]);
        }
        for (int off = 32; off > 0; off >>= 1) f += __shfl_down(f, off, 64);
        if (lane == 0) {
            float Nout = 2048.0f + nout[r];
            float fair = 1.0f;
            if (Nout != 0.0f) {
                float x = f / Nout;
                fair = x < 0.0f ? 0.0f : (x > 1.0f ? 1.0f : x);  // NaN stays
            }
            out[1 + r] = fair;
        }
    }
    if (b == GB - 1) {
        float s = 0.f;
        for (int i = t; i < T; i += BT) {
            float gt = good_buf[targets[i]];
            s += (gt == gt) ? gt : 0.0f;       // NaN -> 0
        }
        for (int off = 32; off > 0; off >>= 1) s += __shfl_down(s, off, 64);
        __syncthreads();
        if (lane == 0) s_acc[wv] = s;
        __syncthreads();
        if (t == 0) out[0] = s_acc[0] + s_acc[1] + s_acc[2] + s_acc[3];
    }
}

extern "C" void kernel_launch(void* const* d_in, const int* in_sizes, int n_in,
                              void* d_out, int out_size, void* d_ws, size_t ws_size,
                              hipStream_t stream) {
    const int2*  edges   = (const int2*)d_in[0];
    const float* weights = (const float*)d_in[1];
    const float* stat    = (const float*)d_in[2];
    const int2*  edges_c = (const int2*)d_in[3];
    const float* grdt    = (const float*)d_in[4];
    const int*   targets = (const int*)d_in[5];
    int E  = in_sizes[1];
    int EC = in_sizes[4];
    int T  = in_sizes[5];
    float* out = (float*)d_out;

    int*    row_cnt  = (int*)d_ws;                          // NN*CPAD
    int*    cnt2     = row_cnt + NN * CPAD;                 // NN
    float*  nout     = (float*)(cnt2 + NN);                 // NN
    float*  good_buf = nout + NN;                           // NN
    float4* rowbuf   = (float4*)(good_buf + NN);            // NN*RCAP float4
    int2*   out_rc   = (int2*)(rowbuf + (size_t)NN * RCAP); // NN*RCAP int2
    float*  part     = (float*)(out_rc + (size_t)NN * RCAP);// NBC*2*NN

    void* args[] = {
        (void*)&edges, (void*)&weights, (void*)&stat, (void*)&edges_c,
        (void*)&grdt, (void*)&targets, (void*)&E, (void*)&EC, (void*)&T,
        (void*)&row_cnt, (void*)&rowbuf, (void*)&out_rc, (void*)&cnt2,
        (void*)&nout, (void*)&part, (void*)&good_buf, (void*)&out
    };
    hipLaunchCooperativeKernel((void*)fused_k, dim3(GB), dim3(BT), args, 0,
                               stream);
}

// Round 11
// 64.474 us; speedup vs baseline: 5.0703x; 5.0703x over previous
//
#include <hip/hip_runtime.h>
#include <math.h>

#define NN 4096
#define RCAP 256          // per-row/col bucket capacity (mean 80, max ~130)
#define CPAD 16           // counter stride in ints: one counter per 64B line
#define CR 4              // rows (or cols) per coalesce block, wave per row
#define HS2 1024          // shared LDS hash slots (load ~31%, worst ~55%)

// mysign(|v|) - 0.5 with reference-faithful overflow: e=inf -> NaN
__device__ __forceinline__ float smh(float v) {
    float e = expf(6.0f * fabsf(v));
    return 0.5f * (e - 1.0f) / (e + 1.0f);
}

// Zero row+col counters (rocclr small-fill kernel is latency-bound).
__global__ __launch_bounds__(256) void zero_k(float4* __restrict__ p) {
    p[blockIdx.x * 256 + threadIdx.x] = make_float4(0.f, 0.f, 0.f, 0.f);
}

// Bucket all records by row AND by column. Payloads are plain 16B stores;
// only the position counters are atomic (padded: 1 counter per cache line).
__global__ __launch_bounds__(256) void bucket_k(
    const int2* __restrict__ edges, const float* __restrict__ weights,
    const float* __restrict__ stat, const int2* __restrict__ edges_c,
    const float* __restrict__ grdt, int* __restrict__ row_cnt,
    int* __restrict__ col_cnt, float4* __restrict__ rowbuf,
    float4* __restrict__ colbuf, int E, int EC) {
    int i = blockIdx.x * 256 + threadIdx.x;
    int2 rc; float f0, f1 = 0.f; int isC;
    if (i < E) {
        rc = edges[i]; f0 = stat[i]; f1 = weights[i]; isC = 0;
    } else if (i < E + EC) {
        int j = i - E;
        rc = edges_c[j]; f0 = grdt[j]; isC = 1;
    } else return;
    float4 rec;
    rec.y = f0;      // stat (A) or grdt (B)
    rec.z = f1;      // weight (W) or unused
    rec.w = 0.f;
    int posr = atomicAdd(&row_cnt[rc.x * CPAD], 1);
    if (posr < RCAP) {
        rec.x = __int_as_float((rc.y << 1) | isC);   // tag = col
        rowbuf[rc.x * RCAP + posr] = rec;
    }
    int posc = atomicAdd(&col_cnt[rc.y * CPAD], 1);
    if (posc < RCAP) {
        rec.x = __int_as_float((rc.x << 1) | isC);   // tag = row
        colbuf[rc.y * RCAP + posc] = rec;
    }
}

// 2048 blocks. Blocks 0..1023: row side -> CSR + cnt2 + nout.
// Blocks 1024..2047: col side -> good directly (g, nin per column).
// Both: wave per row/col, shared 1024-slot LDS hash coalescing duplicate
// cells (scatter-add semantics like the reference), then sweep slots with
// v = B*(A-1) + A*W. No global atomics.
__global__ __launch_bounds__(256) void coal_k(
    const int* __restrict__ row_cnt, const float4* __restrict__ rowbuf,
    const int* __restrict__ col_cnt, const float4* __restrict__ colbuf,
    int2* __restrict__ out_rc, int* __restrict__ cnt2,
    float* __restrict__ nout, float* __restrict__ good_buf,
    float* __restrict__ good_out) {
    __shared__ int hkey[HS2];
    __shared__ float hA[HS2], hW[HS2], hB[HS2];
    __shared__ int s_n[CR];
    __shared__ float acc1[CR], acc2[CR];
    const int tid = threadIdx.x;
    const int wv = tid >> 6, lane = tid & 63;
    const bool isRow = blockIdx.x < NN / CR;
    const int base = (isRow ? blockIdx.x : blockIdx.x - NN / CR) * CR;
    for (int i = tid; i < HS2; i += 256) {
        hkey[i] = -1; hA[i] = 0.f; hW[i] = 0.f; hB[i] = 0.f;
    }
    if (tid < CR) { s_n[tid] = 0; acc1[tid] = 0.f; acc2[tid] = 0.f; }
    __syncthreads();
    {   // wave wv owns row/col base+wv
        int idx = base + wv;
        const int* cntp = isRow ? row_cnt : col_cnt;
        const float4* buf = isRow ? rowbuf : colbuf;
        int cnt = cntp[idx * CPAD];
        if (cnt > RCAP) cnt = RCAP;
        for (int i = lane; i < cnt; i += 64) {
            float4 rec = buf[idx * RCAP + i];
            int ct = __float_as_int(rec.x);
            int key = (wv << 12) | (ct >> 1);
            int slot = (int)(((unsigned)key * 2654435761u) >> 18) & (HS2 - 1);
            while (true) {
                int prev = atomicCAS(&hkey[slot], -1, key);
                if (prev == -1 || prev == key) break;
                slot = (slot + 1) & (HS2 - 1);
            }
            if (ct & 1) {
                atomicAdd(&hB[slot], rec.y);
            } else {
                atomicAdd(&hA[slot], rec.y);
                atomicAdd(&hW[slot], rec.z);
            }
        }
    }
    __syncthreads();
#pragma unroll
    for (int k = 0; k < HS2 / 256; ++k) {      // 4 slots/thread
        int s = k * 256 + tid;
        int key = hkey[s];
        if (key != -1) {
            float a = hA[s], w = hW[s], b = hB[s];
            float v = b * (a - 1.0f) + a * w;
            if (v != 0.0f) {                   // zero cells: 0 to all sums
                int lr = key >> 12;
                atomicAdd(&acc1[lr], smh(v));  // NaN propagates like ref
                if (isRow) {
                    int pos = atomicAdd(&s_n[lr], 1);
                    out_rc[(base + lr) * RCAP + pos] =
                        make_int2(key & 4095, __float_as_int(v));
                } else {
                    atomicAdd(&acc2[lr], v);   // g (column sum)
                }
            }
        }
    }
    __syncthreads();
    if (tid < CR) {
        if (isRow) {
            nout[base + tid] = acc1[tid];
            cnt2[base + tid] = s_n[tid];
        } else {
            // good = clip(g/Nin, -1, 1), NaN-propagating;
            // Nin baseline 2048 = 0.5 * 4096 (mysign(0) = 0.5)
            float Nin = 2048.0f + acc1[tid];
            float gd = 1.0f;
            if (Nin != 0.0f) {
                float x = acc2[tid] / Nin;
                gd = x < -1.0f ? -1.0f : (x > 1.0f ? 1.0f : x);
            }
            good_buf[base + tid] = gd;
            good_out[base + tid] = gd;
        }
    }
}

// Wave per row over the compact (col,v) list (v != 0 mask is implicit);
// last block does the targets gsum.
__global__ __launch_bounds__(256) void fair_k(
    const int* __restrict__ cnt2, const int2* __restrict__ out_rc,
    const float* __restrict__ nout, const float* __restrict__ good_buf,
    const int* __restrict__ targets, int T, float* __restrict__ out) {
    if (blockIdx.x < NN / 4) {
        int wv = threadIdx.x >> 6, lane = threadIdx.x & 63;
        int r = blockIdx.x * 4 + wv;
        int cnt = cnt2[r];
        float f = 0.f;
        for (int i = lane; i < cnt; i += 64) {
            int2 rec = out_rc[r * RCAP + i];
            float v = __int_as_float(rec.y);
            f += 1.0f - 0.5f * fabsf(v - good_buf[rec.x]);
        }
        for (int off = 32; off > 0; off >>= 1) f += __shfl_down(f, off, 64);
        if (lane == 0) {
            float Nout = 2048.0f + nout[r];
            float fair = 1.0f;
            if (Nout != 0.0f) {
                float x = f / Nout;
                fair = x < 0.0f ? 0.0f : (x > 1.0f ? 1.0f : x);  // NaN stays
            }
            out[1 + r] = fair;
        }
    } else {
        float s = 0.f;
        for (int i = threadIdx.x; i < T; i += 256) {
            float gt = good_buf[targets[i]];
            s += (gt == gt) ? gt : 0.0f;   // NaN -> 0
        }
        for (int off = 32; off > 0; off >>= 1) s += __shfl_down(s, off, 64);
        __shared__ float lds[4];
        int lane = threadIdx.x & 63, w = threadIdx.x >> 6;
        if (lane == 0) lds[w] = s;
        __syncthreads();
        if (threadIdx.x == 0) out[0] = lds[0] + lds[1] + lds[2] + lds[3];
    }
}

extern "C" void kernel_launch(void* const* d_in, const int* in_sizes, int n_in,
                              void* d_out, int out_size, void* d_ws, size_t ws_size,
                              hipStream_t stream) {
    const int2*  edges   = (const int2*)d_in[0];
    const float* weights = (const float*)d_in[1];
    const float* stat    = (const float*)d_in[2];
    const int2*  edges_c = (const int2*)d_in[3];
    const float* grdt    = (const float*)d_in[4];
    const int*   targets = (const int*)d_in[5];
    const int E  = in_sizes[1];
    const int EC = in_sizes[4];
    const int T  = in_sizes[5];
    float* out = (float*)d_out;

    int*    row_cnt  = (int*)d_ws;                          // NN*CPAD
    int*    col_cnt  = row_cnt + NN * CPAD;                 // NN*CPAD
    int*    cnt2     = col_cnt + NN * CPAD;                 // NN
    float*  nout     = (float*)(cnt2 + NN);                 // NN
    float*  good_buf = nout + NN;                           // NN
    float4* rowbuf   = (float4*)(good_buf + NN);            // NN*RCAP float4
    float4* colbuf   = rowbuf + (size_t)NN * RCAP;          // NN*RCAP float4
    int2*   out_rc   = (int2*)(colbuf + (size_t)NN * RCAP); // NN*RCAP int2

    // zero row_cnt+col_cnt: 2*NN*CPAD ints = 512KB = 128 blk * 256 t * 16B
    zero_k<<<2 * NN * CPAD / (256 * 4), 256, 0, stream>>>((float4*)row_cnt);

    bucket_k<<<(E + EC + 255) / 256, 256, 0, stream>>>(
        edges, weights, stat, edges_c, grdt, row_cnt, col_cnt,
        rowbuf, colbuf, E, EC);

    coal_k<<<2 * NN / CR, 256, 0, stream>>>(row_cnt, rowbuf, col_cnt, colbuf,
                                            out_rc, cnt2, nout, good_buf,
                                            out + 1 + NN);

    fair_k<<<NN / 4 + 1, 256, 0, stream>>>(cnt2, out_rc, nout, good_buf,
                                           targets, T, out);
}

// Round 12
// 59.173 us; speedup vs baseline: 5.5246x; 1.0896x over previous
//
#include <hip/hip_runtime.h>
#include <math.h>

#define NN 4096
#define RCAP 256          // per-row/col bucket capacity (mean 80, max ~130)
#define CPAD 16           // counter stride in ints: one counter per 64B line
#define CR 4              // rows (or cols) per coalesce block, wave per row
#define HS2 1024          // shared LDS hash slots (load ~31%, worst ~55%)
#define NPART 8           // XCD partitions (blockIdx%8 -> XCD round-robin)
#define PROWS (NN / NPART)   // 512 rows per partition
#define NCHK 128          // input chunks per partition

// mysign(|v|) - 0.5 with reference-faithful overflow: e=inf -> NaN
__device__ __forceinline__ float smh(float v) {
    float e = expf(6.0f * fabsf(v));
    return 0.5f * (e - 1.0f) / (e + 1.0f);
}

// Zero row+col counters (rocclr small-fill kernel is latency-bound).
__global__ __launch_bounds__(256) void zero_k(float4* __restrict__ p) {
    p[blockIdx.x * 256 + threadIdx.x] = make_float4(0.f, 0.f, 0.f, 0.f);
}

// XCD-partitioned bucketing: block (p = blockIdx%8, chunk = blockIdx/8)
// scans chunk `chunk` of the input and keeps records with row (resp. col)
// in partition p. All writes to partition p's rowbuf/colbuf slice come from
// one XCD -> lines stay in that XCD's L2 and write-back coalesced (the
// round-11 counter showed 40MB written for 10.5MB of payload from
// cross-XCD line bouncing). Reads are 8x amplified but L2/L3-resident.
__global__ __launch_bounds__(256) void bucket_k(
    const int2* __restrict__ edges, const float* __restrict__ weights,
    const float* __restrict__ stat, const int2* __restrict__ edges_c,
    const float* __restrict__ grdt, int* __restrict__ row_cnt,
    int* __restrict__ col_cnt, float4* __restrict__ rowbuf,
    float4* __restrict__ colbuf, int E, int EC) {
    const int p = blockIdx.x & (NPART - 1);
    const int chunk = blockIdx.x >> 3;
    const int total = E + EC;
    const int csz = (total + NCHK - 1) / NCHK;
    const int lo = chunk * csz;
    const int hi = min(lo + csz, total);
    const int rlo = p * PROWS, rhi = rlo + PROWS;
    for (int i = lo + threadIdx.x; i < hi; i += 256) {
        int2 rc; int isC;
        if (i < E) { rc = edges[i]; isC = 0; }
        else { rc = edges_c[i - E]; isC = 1; }
        bool rowHit = (rc.x >= rlo && rc.x < rhi);
        bool colHit = (rc.y >= rlo && rc.y < rhi);
        if (!rowHit && !colHit) continue;
        float4 rec;
        if (isC) { rec.y = grdt[i - E]; rec.z = 0.f; }
        else { rec.y = stat[i]; rec.z = weights[i]; }
        rec.w = 0.f;
        if (rowHit) {
            int pos = atomicAdd(&row_cnt[rc.x * CPAD], 1);
            if (pos < RCAP) {
                rec.x = __int_as_float((rc.y << 1) | isC);   // tag = col
                rowbuf[rc.x * RCAP + pos] = rec;
            }
        }
        if (colHit) {
            int pos = atomicAdd(&col_cnt[rc.y * CPAD], 1);
            if (pos < RCAP) {
                rec.x = __int_as_float((rc.x << 1) | isC);   // tag = row
                colbuf[rc.y * RCAP + pos] = rec;
            }
        }
    }
}

// 2048 blocks, XCD-swizzled: row/col base = (j%8)*512 + (j/8)*4 so each
// block reads the bucket slice its own XCD's L2 holds.
// Blocks 0..1023: row side -> CSR + cnt2 + nout.
// Blocks 1024..2047: col side -> good directly (g, nin per column).
// Wave per row/col, shared 1024-slot LDS hash coalescing duplicate cells
// (scatter-add semantics like the reference); sweep: v = B*(A-1) + A*W.
__global__ __launch_bounds__(256) void coal_k(
    const int* __restrict__ row_cnt, const float4* __restrict__ rowbuf,
    const int* __restrict__ col_cnt, const float4* __restrict__ colbuf,
    int2* __restrict__ out_rc, int* __restrict__ cnt2,
    float* __restrict__ nout, float* __restrict__ good_buf,
    float* __restrict__ good_out) {
    __shared__ int hkey[HS2];
    __shared__ float hA[HS2], hW[HS2], hB[HS2];
    __shared__ int s_n[CR];
    __shared__ float acc1[CR], acc2[CR];
    const int tid = threadIdx.x;
    const int wv = tid >> 6, lane = tid & 63;
    const bool isRow = blockIdx.x < NN / CR;
    const int j = isRow ? blockIdx.x : blockIdx.x - NN / CR;
    const int base = (j & (NPART - 1)) * PROWS + (j >> 3) * CR;
    for (int i = tid; i < HS2; i += 256) {
        hkey[i] = -1; hA[i] = 0.f; hW[i] = 0.f; hB[i] = 0.f;
    }
    if (tid < CR) { s_n[tid] = 0; acc1[tid] = 0.f; acc2[tid] = 0.f; }
    __syncthreads();
    {   // wave wv owns row/col base+wv
        int idx = base + wv;
        const int* cntp = isRow ? row_cnt : col_cnt;
        const float4* buf = isRow ? rowbuf : colbuf;
        int cnt = cntp[idx * CPAD];
        if (cnt > RCAP) cnt = RCAP;
        for (int i = lane; i < cnt; i += 64) {
            float4 rec = buf[idx * RCAP + i];
            int ct = __float_as_int(rec.x);
            int key = (wv << 12) | (ct >> 1);
            int slot = (int)(((unsigned)key * 2654435761u) >> 18) & (HS2 - 1);
            while (true) {
                int prev = atomicCAS(&hkey[slot], -1, key);
                if (prev == -1 || prev == key) break;
                slot = (slot + 1) & (HS2 - 1);
            }
            if (ct & 1) {
                atomicAdd(&hB[slot], rec.y);
            } else {
                atomicAdd(&hA[slot], rec.y);
                atomicAdd(&hW[slot], rec.z);
            }
        }
    }
    __syncthreads();
#pragma unroll
    for (int k = 0; k < HS2 / 256; ++k) {      // 4 slots/thread
        int s = k * 256 + tid;
        int key = hkey[s];
        if (key != -1) {
            float a = hA[s], w = hW[s], b = hB[s];
            float v = b * (a - 1.0f) + a * w;
            if (v != 0.0f) {                   // zero cells: 0 to all sums
                int lr = key >> 12;
                atomicAdd(&acc1[lr], smh(v));  // NaN propagates like ref
                if (isRow) {
                    int pos = atomicAdd(&s_n[lr], 1);
                    out_rc[(base + lr) * RCAP + pos] =
                        make_int2(key & 4095, __float_as_int(v));
                } else {
                    atomicAdd(&acc2[lr], v);   // g (column sum)
                }
            }
        }
    }
    __syncthreads();
    if (tid < CR) {
        if (isRow) {
            nout[base + tid] = acc1[tid];
            cnt2[base + tid] = s_n[tid];
        } else {
            // good = clip(g/Nin, -1, 1), NaN-propagating;
            // Nin baseline 2048 = 0.5 * 4096 (mysign(0) = 0.5)
            float Nin = 2048.0f + acc1[tid];
            float gd = 1.0f;
            if (Nin != 0.0f) {
                float x = acc2[tid] / Nin;
                gd = x < -1.0f ? -1.0f : (x > 1.0f ? 1.0f : x);
            }
            good_buf[base + tid] = gd;
            good_out[base + tid] = gd;
        }
    }
}

// Wave per row over the compact (col,v) list, XCD-swizzled like coal_k;
// last block does the targets gsum.
__global__ __launch_bounds__(256) void fair_k(
    const int* __restrict__ cnt2, const int2* __restrict__ out_rc,
    const float* __restrict__ nout, const float* __restrict__ good_buf,
    const int* __restrict__ targets, int T, float* __restrict__ out) {
    if (blockIdx.x < NN / 4) {
        int wv = threadIdx.x >> 6, lane = threadIdx.x & 63;
        int base = (blockIdx.x & (NPART - 1)) * PROWS
                 + (blockIdx.x >> 3) * CR;
        int r = base + wv;
        int cnt = cnt2[r];
        float f = 0.f;
        for (int i = lane; i < cnt; i += 64) {
            int2 rec = out_rc[r * RCAP + i];
            float v = __int_as_float(rec.y);
            f += 1.0f - 0.5f * fabsf(v - good_buf[rec.x]);
        }
        for (int off = 32; off > 0; off >>= 1) f += __shfl_down(f, off, 64);
        if (lane == 0) {
            float Nout = 2048.0f + nout[r];
            float fair = 1.0f;
            if (Nout != 0.0f) {
                float x = f / Nout;
                fair = x < 0.0f ? 0.0f : (x > 1.0f ? 1.0f : x);  // NaN stays
            }
            out[1 + r] = fair;
        }
    } else {
        float s = 0.f;
        for (int i = threadIdx.x; i < T; i += 256) {
            float gt = good_buf[targets[i]];
            s += (gt == gt) ? gt : 0.0f;   // NaN -> 0
        }
        for (int off = 32; off > 0; off >>= 1) s += __shfl_down(s, off, 64);
        __shared__ float lds[4];
        int lane = threadIdx.x & 63, w = threadIdx.x >> 6;
        if (lane == 0) lds[w] = s;
        __syncthreads();
        if (threadIdx.x == 0) out[0] = lds[0] + lds[1] + lds[2] + lds[3];
    }
}

extern "C" void kernel_launch(void* const* d_in, const int* in_sizes, int n_in,
                              void* d_out, int out_size, void* d_ws, size_t ws_size,
                              hipStream_t stream) {
    const int2*  edges   = (const int2*)d_in[0];
    const float* weights = (const float*)d_in[1];
    const float* stat    = (const float*)d_in[2];
    const int2*  edges_c = (const int2*)d_in[3];
    const float* grdt    = (const float*)d_in[4];
    const int*   targets = (const int*)d_in[5];
    const int E  = in_sizes[1];
    const int EC = in_sizes[4];
    const int T  = in_sizes[5];
    float* out = (float*)d_out;

    int*    row_cnt  = (int*)d_ws;                          // NN*CPAD
    int*    col_cnt  = row_cnt + NN * CPAD;                 // NN*CPAD
    int*    cnt2     = col_cnt + NN * CPAD;                 // NN
    float*  nout     = (float*)(cnt2 + NN);                 // NN
    float*  good_buf = nout + NN;                           // NN
    float4* rowbuf   = (float4*)(good_buf + NN);            // NN*RCAP float4
    float4* colbuf   = rowbuf + (size_t)NN * RCAP;          // NN*RCAP float4
    int2*   out_rc   = (int2*)(colbuf + (size_t)NN * RCAP); // NN*RCAP int2

    // zero row_cnt+col_cnt: 2*NN*CPAD ints = 512KB = 128 blk * 256 t * 16B
    zero_k<<<2 * NN * CPAD / (256 * 4), 256, 0, stream>>>((float4*)row_cnt);

    bucket_k<<<NPART * NCHK, 256, 0, stream>>>(
        edges, weights, stat, edges_c, grdt, row_cnt, col_cnt,
        rowbuf, colbuf, E, EC);

    coal_k<<<2 * NN / CR, 256, 0, stream>>>(row_cnt, rowbuf, col_cnt, colbuf,
                                            out_rc, cnt2, nout, good_buf,
                                            out + 1 + NN);

    fair_k<<<NN / 4 + 1, 256, 0, stream>>>(cnt2, out_rc, nout, good_buf,
                                           targets, T, out);
}